// Round 2
// baseline (52.781 us; speedup 1.0000x reference)
//
#include <hip/hip_runtime.h>
#include <hip/hip_bf16.h>
#include <math.h>

#define HW 16384          // H*W
#define NCH 64            // C

// PWL table: per channel, o_j(x) sampled on uniform grid [-8,8), N=2048.
#define NG   2048
#define X0   (-8.0f)
#define INVDX 128.0f      // 1/DX
#define DX   0.0078125f   // 16/2048
#define PSTR (64*2048)    // plane stride (floats): [j][c][pt]

typedef __attribute__((ext_vector_type(8))) short s16x8;
typedef __attribute__((ext_vector_type(4))) short s16x4;
typedef __attribute__((ext_vector_type(2))) float f32x2;
typedef __attribute__((ext_vector_type(4))) float f32x4;
typedef __attribute__((ext_vector_type(8))) float f32x8;
typedef __attribute__((ext_vector_type(2))) __bf16 bf16x2;
typedef __attribute__((ext_vector_type(8))) __bf16 bf16x8;
typedef __attribute__((ext_vector_type(4))) unsigned u32x4;
typedef __attribute__((ext_vector_type(2))) unsigned u32x2;

__device__ __forceinline__ short bf16b(float f) {
    union { __hip_bfloat16 h; short s; } u;
    u.h = __float2bfloat16(f);
    return u.s;
}
__device__ __forceinline__ float bf2f(unsigned short us) {
    union { unsigned u; float f; } x;
    x.u = ((unsigned)us) << 16;
    return x.f;
}
__device__ __forceinline__ s16x8 cvt8(f32x8 v) {
    return __builtin_bit_cast(s16x8, __builtin_convertvector(v, bf16x8));
}
__device__ __forceinline__ unsigned pk_h1(f32x2 xw, f32x2 w, f32x2 b, f32x2 z2) {
    const f32x2 h = __builtin_elementwise_max(__builtin_elementwise_fma(xw, w, b), z2);
    return __builtin_bit_cast(unsigned, __builtin_convertvector(h, bf16x2));
}
__device__ __forceinline__ unsigned pk_relu_cvt(f32x2 v, f32x2 z2) {
    const f32x2 g = __builtin_elementwise_max(v, z2);
    return __builtin_bit_cast(unsigned, __builtin_convertvector(g, bf16x2));
}

#if __has_builtin(__builtin_amdgcn_mfma_f32_16x16x16bf16_1k)
#define HAVE_MFMA16 1
#else
#define HAVE_MFMA16 0
#endif

// ---------------- Phase 0: tabulate per-channel KAN maps on the grid ------
__global__ __launch_bounds__(64, 4) void kan_grid_mfma(
    const float* __restrict__ W1,   // [64][64]
    const float* __restrict__ b1,   // [64][64]
    const float* __restrict__ W2,   // [64][64][64]
    const float* __restrict__ b2,   // [64][64]
    const float* __restrict__ W3,   // [64][64][3]
    const float* __restrict__ b3,   // [64][3]
    float* __restrict__ table)      // [3][64][2048]
{
    const int c     = blockIdx.x & 63;
    const int chunk = blockIdx.x >> 6;       // 0..7, 256 grid pts each
    const int lane  = threadIdx.x;           // 0..63
    const int l15   = lane & 15;
    const int grp   = lane >> 4;

    __shared__ float W2s[4096];              // 16KB: W2c staged coalesced
    __shared__ float W1s[64], B1s[64], B2s[64];
    {
        const float4* src = (const float4*)(W2 + c * 4096);
        float4* dst = (float4*)W2s;
        for (int i = lane; i < 1024; i += 64) dst[i] = src[i];
        W1s[lane] = W1[c*64 + lane];
        B1s[lane] = b1[c*64 + lane];
        B2s[lane] = b2[c*64 + lane];
    }
    __syncthreads();

    const float* W3c = W3 + c * 192;

    // A1 = W2T frags from LDS (broadcast reads)
    s16x8 a1[4][2];
#pragma unroll
    for (int m = 0; m < 4; ++m)
#pragma unroll
        for (int s = 0; s < 2; ++s) {
            f32x8 w;
#pragma unroll
            for (int jj = 0; jj < 8; ++jj)
                w[jj] = W2s[(s*32 + grp*8 + jj)*64 + m*16 + l15];
            a1[m][s] = cvt8(w);
        }

#if HAVE_MFMA16
    s16x4 a2[4];
#pragma unroll
    for (int m = 0; m < 4; ++m) {
        s16x4 f;
#pragma unroll
        for (int jj = 0; jj < 4; ++jj) {
            const int k = m*16 + grp*4 + jj;
            f[jj] = (l15 < 3) ? bf16b(W3c[k*3 + l15]) : (short)0;
        }
        a2[m] = f;
    }
    f32x4 b3r;
#pragma unroll
    for (int r = 0; r < 4; ++r) {
        const int row = grp*4 + r;
        b3r[r] = (row < 3) ? b3[c*3 + row] : 0.f;
    }
#else
    const float b3v0 = b3[c*3+0], b3v1 = b3[c*3+1], b3v2 = b3[c*3+2];
#endif

    float* Tq = table + c*NG;
    const char* b2base = (const char*)B2s;
    const f32x2 z2 = {0.f, 0.f};

    for (int t = 0; t < 16; ++t) {
        int z;
        asm volatile("v_mov_b32 %0, 0" : "=v"(z));

        const int pt = chunk*256 + t*16 + l15;
        const float xv = X0 + (float)pt * DX;
        const f32x2 xw = {xv, xv};

        s16x8 bf[2];
#pragma unroll
        for (int s = 0; s < 2; ++s) {
            const f32x4 w1lo = *(const f32x4*)&W1s[z + s*32 + grp*8];
            const f32x4 w1hi = *(const f32x4*)&W1s[z + s*32 + grp*8 + 4];
            const f32x4 b1lo = *(const f32x4*)&B1s[z + s*32 + grp*8];
            const f32x4 b1hi = *(const f32x4*)&B1s[z + s*32 + grp*8 + 4];
            u32x4 p;
            p[0] = pk_h1(xw, (f32x2){w1lo[0], w1lo[1]}, (f32x2){b1lo[0], b1lo[1]}, z2);
            p[1] = pk_h1(xw, (f32x2){w1lo[2], w1lo[3]}, (f32x2){b1lo[2], b1lo[3]}, z2);
            p[2] = pk_h1(xw, (f32x2){w1hi[0], w1hi[1]}, (f32x2){b1hi[0], b1hi[1]}, z2);
            p[3] = pk_h1(xw, (f32x2){w1hi[2], w1hi[3]}, (f32x2){b1hi[2], b1hi[3]}, z2);
            bf[s] = __builtin_bit_cast(s16x8, p);
        }

        f32x4 acc[4];
#pragma unroll
        for (int m = 0; m < 4; ++m) {
            acc[m] = *(const f32x4*)(b2base + (m*64 + grp*16 + z));
            acc[m] = __builtin_amdgcn_mfma_f32_16x16x32_bf16(a1[m][0], bf[0], acc[m], 0, 0, 0);
            acc[m] = __builtin_amdgcn_mfma_f32_16x16x32_bf16(a1[m][1], bf[1], acc[m], 0, 0, 0);
        }

#if HAVE_MFMA16
        s16x4 bb[4];
#pragma unroll
        for (int m = 0; m < 4; ++m) {
            u32x2 pv;
            pv[0] = pk_relu_cvt((f32x2){acc[m][0], acc[m][1]}, z2);
            pv[1] = pk_relu_cvt((f32x2){acc[m][2], acc[m][3]}, z2);
            bb[m] = __builtin_bit_cast(s16x4, pv);
        }
        f32x4 acc2a = b3r;
        f32x4 acc2b = {0.f, 0.f, 0.f, 0.f};
        acc2a = __builtin_amdgcn_mfma_f32_16x16x16bf16_1k(a2[0], bb[0], acc2a, 0, 0, 0);
        acc2b = __builtin_amdgcn_mfma_f32_16x16x16bf16_1k(a2[1], bb[1], acc2b, 0, 0, 0);
        acc2a = __builtin_amdgcn_mfma_f32_16x16x16bf16_1k(a2[2], bb[2], acc2a, 0, 0, 0);
        acc2b = __builtin_amdgcn_mfma_f32_16x16x16bf16_1k(a2[3], bb[3], acc2b, 0, 0, 0);
        if (grp == 0) {
            Tq[pt]          = acc2a[0] + acc2b[0];
            Tq[PSTR + pt]   = acc2a[1] + acc2b[1];
            Tq[2*PSTR + pt] = acc2a[2] + acc2b[2];
        }
#else
        float po0 = 0.f, po1 = 0.f, po2 = 0.f;
#pragma unroll
        for (int m = 0; m < 4; ++m)
#pragma unroll
            for (int r = 0; r < 4; ++r) {
                const float g = fmaxf(acc[m][r], 0.f);
                const int k = m*16 + grp*4 + r;
                po0 = fmaf(g, W3c[k*3+0], po0);
                po1 = fmaf(g, W3c[k*3+1], po1);
                po2 = fmaf(g, W3c[k*3+2], po2);
            }
        po0 += __shfl_xor(po0, 16, 64); po0 += __shfl_xor(po0, 32, 64);
        po1 += __shfl_xor(po1, 16, 64); po1 += __shfl_xor(po1, 32, 64);
        po2 += __shfl_xor(po2, 16, 64); po2 += __shfl_xor(po2, 32, 64);
        if (grp == 0) {
            Tq[pt]          = po0 + b3v0;
            Tq[PSTR + pt]   = po1 + b3v1;
            Tq[2*PSTR + pt] = po2 + b3v2;
        }
#endif
    }
}

// ---------------- Phase 1a: head-major Gram via MFMA (q,k never hit HBM) --
// Channel interleave: attention channel m <-> global qkv channel gm
// (q: gm=m, k: gm=64+m, v: gm=128+m) <-> KAN channel c=gm/3, table plane
// j=gm%3 (torch.cat reshape semantics).
// Block = (b, head, 1024-px split). LDS: q+k bf16 tables for the head's 8
// channels (exactly 64KB). Per 32-px slab: stacked [q;k] 16x32 bf16 frag,
// D += frag x frag^T via mfma_16x16x32 -> 16x16 Gram (qk cross + qq/kk diag).
__global__ __launch_bounds__(512) void gram_kernel(
    const float* __restrict__ x, const float* __restrict__ table,
    float* __restrict__ dpart)
{
    const int bhd = blockIdx.x >> 4;         // 0..15 (b*8+hd)
    const int spl = blockIdx.x & 15;         // 16 splits x 1024 px
    const int b = bhd >> 3, hd = bhd & 7;
    const int tid = threadIdx.x;             // 0..511
    const int w   = tid >> 6;                // wave 0..7
    const int l   = tid & 63;
    const int grp = l >> 4;                  // k-group 0..3
    const int i16 = l & 15;                  // Gram row/col 0..15
    const int ch  = i16 & 7;                 // channel within head
    const int usek = i16 >> 3;               // 0 = q row, 1 = k row

    __shared__ unsigned short T[2][8][NG];   // 64KB bf16 tables (q,k x 8ch)

    // stage + convert: 2 maps x 8 ch x 2048 f32 -> bf16 (8192 float4 total)
    for (int e = tid; e < 8192; e += 512) {
        const int map = e >> 12;             // 0=q slot, 1=k slot
        const int rem = e & 4095;
        const int c8  = rem >> 9;            // 512 float4 per channel slot
        const int g   = rem & 511;
        const int gm  = map*64 + hd*8 + c8;  // global qkv channel
        const int cc  = gm / 3;              // KAN channel
        const int jj  = gm % 3;              // table plane
        const float4 v = ((const float4*)(table + jj*PSTR + cc*NG))[g];
        u32x2 pk;
        pk[0] = ((unsigned)(unsigned short)bf16b(v.x)) | (((unsigned)(unsigned short)bf16b(v.y)) << 16);
        pk[1] = ((unsigned)(unsigned short)bf16b(v.z)) | (((unsigned)(unsigned short)bf16b(v.w)) << 16);
        *(u32x2*)&T[map][c8][g*4] = pk;
    }
    __syncthreads();

    const unsigned short* Tc = T[usek][ch];
    const int gm = usek*64 + hd*8 + ch;      // this row's global channel
    const int cx = gm / 3;                   // input x channel
    const float* xp = x + (b*NCH + cx)*HW + spl*1024 + grp*8;

    f32x4 gacc = {0.f, 0.f, 0.f, 0.f};
#pragma unroll
    for (int s = 0; s < 4; ++s) {
        const int slab = w*4 + s;            // 0..31 (32 slabs of 32 px)
        const float* xs = xp + slab*32;
        const f32x4 xlo = *(const f32x4*)xs;
        const f32x4 xhi = *(const f32x4*)(xs + 4);
        f32x8 vals;
#pragma unroll
        for (int e = 0; e < 8; ++e) {
            const float xv = (e < 4) ? xlo[e] : xhi[e-4];
            const float u = (xv - X0) * INVDX;
            int idx = (int)u;
            idx = min(max(idx, 0), NG - 2);
            const float fr = u - (float)idx;
            const float t0 = bf2f(Tc[idx]);
            const float t1 = bf2f(Tc[idx+1]);
            vals[e] = fmaf(fr, t1 - t0, t0);
        }
        const s16x8 frag = cvt8(vals);
        gacc = __builtin_amdgcn_mfma_f32_16x16x32_bf16(frag, frag, gacc, 0, 0, 0);
    }

    // cross-wave reduce of the 16x16 Gram (tables dead -> reuse LDS)
    __syncthreads();
    float* red = (float*)&T[0][0][0];        // 8 waves x 256 floats = 8KB
#pragma unroll
    for (int r = 0; r < 4; ++r)
        red[w*256 + (grp*4 + r)*16 + i16] = gacc[r];
    __syncthreads();

    if (tid < 256) {
        const int row = tid >> 4, col = tid & 15;
        float g = 0.f;
#pragma unroll
        for (int ww = 0; ww < 8; ++ww) g += red[ww*256 + tid];
        int p = -1;
        if (row < 8 && col >= 8)      p = row*8 + (col - 8);   // q_i . k_j
        else if (row == col && row < 8) p = 64 + row;          // q_i . q_i
        else if (row == col)            p = 72 + (row - 8);    // k_j . k_j
        if (p >= 0) dpart[(bhd*16 + spl)*80 + p] = g;
    }
}

// ---------------- Phase 1b: evaluate v only, store bf16 -------------------
__global__ __launch_bounds__(256) void v_eval(
    const float* __restrict__ x, const float* __restrict__ table,
    unsigned short* __restrict__ vbuf)
{
    const int m     = blockIdx.x >> 3;       // v-channel 0..63
    const int chunk = blockIdx.x & 7;        // 8 chunks x 4096 px
    const int t     = threadIdx.x;
    const int gm    = 128 + m;               // global qkv channel
    const int cx    = gm / 3;                // KAN / x channel
    const int jj    = gm % 3;                // table plane

    __shared__ float Lv[NG];
    const float4* Tv = (const float4*)(table + jj*PSTR + cx*NG);
    for (int i = t; i < NG/4; i += 256) ((float4*)Lv)[i] = Tv[i];
    __syncthreads();

    const int pxbase = chunk * 4096;         // never crosses batch
    const int b  = pxbase >> 14;
    const int hw = pxbase & 16383;
    const float* xr = x + (b*NCH + cx)*HW + hw;
    unsigned short* vr = vbuf + (b*NCH + m)*HW + hw;

    for (int i = 0; i < 8; ++i) {
        const int off = i*512 + t*2;
        const float2 xv = *(const float2*)(xr + off);
        float o[2];
#pragma unroll
        for (int e = 0; e < 2; ++e) {
            const float u = ((e ? xv.y : xv.x) - X0) * INVDX;
            int idx = (int)u;
            idx = min(max(idx, 0), NG - 2);
            const float fr = u - (float)idx;
            const float v0 = Lv[idx], v1 = Lv[idx+1];
            o[e] = fmaf(fr, v1 - v0, v0);
        }
        ushort2 vs;
        vs.x = (unsigned short)bf16b(o[0]);
        vs.y = (unsigned short)bf16b(o[1]);
        *(ushort2*)(vr + off) = vs;
    }
}

// ---------------- Phase 3: fused attn (softmax+Wout fold) + output GEMM ----
__global__ __launch_bounds__(256) void out_kernel(
    const unsigned short* __restrict__ vbuf, const float* __restrict__ dpart,
    const float* __restrict__ temp, const float* __restrict__ Wout,
    const float* __restrict__ bout, float* __restrict__ out)
{
    const int b    = blockIdx.x >> 8;          // 2
    const int qtr  = (blockIdx.x >> 6) & 3;    // 4 quarters of 16 outs
    const int tile = blockIdx.x & 63;          // 64 tiles of 256 px
    const int n = tile * 256 + threadIdx.x;
    const int t = threadIdx.x;                 // 0..255

    __shared__ float D[8][80];
    __shared__ float attnS[8][8][8];
    __shared__ float4 AtS[64][4];              // At[cv][qtr*16 .. +16)

    for (int idx = t; idx < 640; idx += 256) {
        const int g = idx / 80, p = idx % 80;
        float s = 0.f;
        for (int spl = 0; spl < 16; ++spl)
            s += dpart[((b*8 + g)*16 + spl)*80 + p];
        D[g][p] = s;
    }
    __syncthreads();

    if (t < 64) {
        const int hd = t >> 3, i = t & 7;
        const float invq = 1.f / fmaxf(sqrtf(D[hd][64+i]), 1e-12f);
        const float T = temp[hd];
        float l[8];
        float m = -1e30f;
#pragma unroll
        for (int j = 0; j < 8; ++j) {
            const float invk = 1.f / fmaxf(sqrtf(D[hd][72+j]), 1e-12f);
            l[j] = D[hd][i*8+j] * invq * invk * T;
            m = fmaxf(m, l[j]);
        }
        float s = 0.f;
#pragma unroll
        for (int j = 0; j < 8; ++j) { l[j] = expf(l[j] - m); s += l[j]; }
        const float inv = 1.f / s;
#pragma unroll
        for (int j = 0; j < 8; ++j) attnS[hd][i][j] = l[j] * inv;
    }
    __syncthreads();

    {
        const int cv = t & 63, oq = t >> 6;       // oq in {0..3}
        const int hd = cv >> 3, jj = cv & 7;
        float res[4];
#pragma unroll
        for (int oo = 0; oo < 4; ++oo) {
            const int o = qtr*16 + oq*4 + oo;
            float s = 0.f;
#pragma unroll
            for (int i = 0; i < 8; ++i)
                s = fmaf(Wout[o*64 + hd*8 + i], attnS[hd][i][jj], s);
            res[oo] = s;
        }
        AtS[cv][oq] = make_float4(res[0], res[1], res[2], res[3]);
    }
    __syncthreads();

    float acc[16];
#pragma unroll
    for (int o = 0; o < 16; ++o) acc[o] = 0.f;

    const unsigned short* vbase = vbuf + (b*NCH)*HW + n;
    for (int cv = 0; cv < 64; ++cv) {
        const float vv = bf2f(vbase[cv*HW]);
#pragma unroll
        for (int o4 = 0; o4 < 4; ++o4) {
            const float4 w = AtS[cv][o4];
            acc[4*o4+0] = fmaf(w.x, vv, acc[4*o4+0]);
            acc[4*o4+1] = fmaf(w.y, vv, acc[4*o4+1]);
            acc[4*o4+2] = fmaf(w.z, vv, acc[4*o4+2]);
            acc[4*o4+3] = fmaf(w.w, vv, acc[4*o4+3]);
        }
    }
#pragma unroll
    for (int o = 0; o < 16; ++o) {
        const int oc = qtr*16 + o;
        out[(b*NCH + oc)*HW + n] = acc[o] + bout[oc];
    }
}

// ---------------- launcher ----------------
extern "C" void kernel_launch(void* const* d_in, const int* in_sizes, int n_in,
                              void* d_out, int out_size, void* d_ws, size_t ws_size,
                              hipStream_t stream) {
    const float* x    = (const float*)d_in[0];
    const float* W1   = (const float*)d_in[1];
    const float* b1   = (const float*)d_in[2];
    const float* W2   = (const float*)d_in[3];
    const float* b2   = (const float*)d_in[4];
    const float* W3   = (const float*)d_in[5];
    const float* b3   = (const float*)d_in[6];
    const float* temp = (const float*)d_in[7];
    const float* Wout = (const float*)d_in[8];
    const float* bout = (const float*)d_in[9];
    float* out = (float*)d_out;

    float* ws = (float*)d_ws;
    float* table = ws;                               // 3*64*2048 = 393216 f32
    float* dpart = ws + 393216;                      // 256*80 = 20480 f32
    unsigned short* vbuf = (unsigned short*)(ws + 393216 + 20480); // 2*64*16384 bf16

    kan_grid_mfma<<<512, 64, 0, stream>>>(W1, b1, W2, b2, W3, b3, table);
    gram_kernel<<<256, 512, 0, stream>>>(x, table, dpart);
    v_eval<<<512, 256, 0, stream>>>(x, table, vbuf);
    out_kernel<<<512, 256, 0, stream>>>(vbuf, dpart, temp, Wout, bout, out);
}